// Round 7
// baseline (358.262 us; speedup 1.0000x reference)
//
#include <hip/hip_runtime.h>

// SymHQLinear: out[8192,4096] = x @ W^T; W[4096,4096] dequantized from
// codebook[4096,8] + per-row scales + packed sign bits.
#define M_ 8192   // TOKENS
#define N_ 4096   // OUT
#define K_ 4096   // IN

typedef __bf16 bf16x8 __attribute__((ext_vector_type(8)));
typedef float  f32x4  __attribute__((ext_vector_type(4)));

__device__ __forceinline__ unsigned short f2bf(float f) {
  unsigned u = __builtin_bit_cast(unsigned, f);
  unsigned r = 0x7fffu + ((u >> 16) & 1u);
  return (unsigned short)((u + r) >> 16);
}

// ---------------------------------------------------------------------------
// Kernel 1: dequantize W -> bf16 [N_][K_]
// ---------------------------------------------------------------------------
__global__ __launch_bounds__(256) void dequant_w_kernel(
    const float* __restrict__ cb, const float* __restrict__ scales,
    const int* __restrict__ idx, const int* __restrict__ signs,
    unsigned short* __restrict__ Wb)
{
  const int g   = blockIdx.x * 256 + threadIdx.x;
  const int row = g >> 9;                           // 512 groups per row
  const int code = idx[g];
  const int sb   = signs[g];
  const float s  = scales[row];
  const float* cv = cb + code * 8;

  unsigned short h[8];
#pragma unroll
  for (int j = 0; j < 8; ++j) {
    float v = cv[j] * s;
    if (!((sb >> (7 - j)) & 1)) v = -v;
    h[j] = f2bf(v);
  }
  uint4 o;
  o.x = (unsigned)h[0] | ((unsigned)h[1] << 16);
  o.y = (unsigned)h[2] | ((unsigned)h[3] << 16);
  o.z = (unsigned)h[4] | ((unsigned)h[5] << 16);
  o.w = (unsigned)h[6] | ((unsigned)h[7] << 16);
  *(uint4*)(Wb + (size_t)g * 8) = o;
}

// ---------------------------------------------------------------------------
// Kernel 2: cast x fp32 -> bf16
// ---------------------------------------------------------------------------
__global__ __launch_bounds__(256) void cvt_x_kernel(
    const float* __restrict__ x, unsigned short* __restrict__ Xb)
{
  const size_t i = (size_t)blockIdx.x * 256 + threadIdx.x;
  const f32x4* px = (const f32x4*)(x + i * 8);
  f32x4 a = px[0], b = px[1];
  uint4 o;
  o.x = (unsigned)f2bf(a[0]) | ((unsigned)f2bf(a[1]) << 16);
  o.y = (unsigned)f2bf(a[2]) | ((unsigned)f2bf(a[3]) << 16);
  o.z = (unsigned)f2bf(b[0]) | ((unsigned)f2bf(b[1]) << 16);
  o.w = (unsigned)f2bf(b[2]) | ((unsigned)f2bf(b[3]) << 16);
  *(uint4*)(Xb + i * 8) = o;
}

// ---------------------------------------------------------------------------
// Kernel 3: 128x256x64 GEMM, 4 waves/WG, B-through-REGISTERS (LDS holds A
// only, 32 KiB/WG -> 2 WGs/CU co-resident = independent barrier domains).
// Per wave: output 128x64; per tile: 16 ds_read_b128 (A) + 8 global dwordx4
// (B->reg) ; staging 4 GLDS (A only).  LDS traffic -33% vs R6 (the measured
// binding constraint).  vmcnt groups per tile: [B:8][A:4]; vmcnt(12) at tile
// end drains tile t+1's B+A exactly.  2-tile unroll (named bE/bO, rule #20).
// ---------------------------------------------------------------------------
#define BM 128
#define BN 256
#define BK 64
#define NT (K_ / BK)          // 64 K-tiles

#define GLDS(g, l) __builtin_amdgcn_global_load_lds( \
    (const __attribute__((address_space(1))) void*)(g), \
    (__attribute__((address_space(3))) void*)(l), 16, 0, 0)

#define LGKM0 do { \
    asm volatile("s_waitcnt lgkmcnt(0)" ::: "memory"); \
    __builtin_amdgcn_sched_barrier(0); \
  } while (0)

#define VMCNT(n) do { \
    asm volatile("s_waitcnt vmcnt(" #n ")" ::: "memory"); \
    __builtin_amdgcn_sched_barrier(0); \
  } while (0)

#define MEMFENCE asm volatile("" ::: "memory")

__global__ __launch_bounds__(256, 2) void gemm128_kernel(
    const unsigned short* __restrict__ A,   // Xb [M_][K_]
    const unsigned short* __restrict__ B,   // Wb [N_][K_]
    float* __restrict__ C)
{
  __shared__ unsigned short lds[2][8192];   // 32 KiB: 2 bufs of 128x64 A

  // XCD-aware swizzle (nwg = 1024, %8 == 0); tm fastest so the 64 consecutive
  // wgs on one XCD share the same B panel (2 MB -> L2 resident).
  const int nwg = (M_ / BM) * (N_ / BN);    // 64*16 = 1024
  const int bid = blockIdx.x;
  const int wg  = (bid % 8) * (nwg / 8) + bid / 8;
  const int tm  = wg % (M_ / BM);
  const int tn  = wg / (M_ / BM);
  const int brow = tm * BM, bcol = tn * BN;

  const int tid  = threadIdx.x;
  const int lane = tid & 63, wn = tid >> 6;  // 4 waves, each owns 64 N-cols
  const int lrow = lane & 15, hi2 = lane >> 4, sw = lrow & 7;
  const int srow2 = tid >> 3;                // staging row base (0..31)
  const int scw8  = ((tid & 7) ^ ((tid >> 3) & 7)) * 8;  // inv-swizzled col

  const unsigned short* Ag = A + (size_t)brow * K_;
  const unsigned short* Bw = B + (size_t)(bcol + wn * 64 + lrow) * K_ + hi2 * 8;

  f32x4 acc[8][4];
#pragma unroll
  for (int m = 0; m < 8; ++m)
#pragma unroll
    for (int n = 0; n < 4; ++n)
      acc[m][n] = f32x4{0.f, 0.f, 0.f, 0.f};

  bf16x8 aq[4][2], bE[4][2], bO[4][2];

#define LOADB(dstv, koff) do { \
    _Pragma("unroll") for (int n_ = 0; n_ < 4; ++n_) \
    _Pragma("unroll") for (int ks_ = 0; ks_ < 2; ++ks_) \
      dstv[n_][ks_] = *(const bf16x8*)(const void*)( \
          Bw + (size_t)n_ * 16 * K_ + (koff) + ks_ * 32); \
  } while (0)

#define STAGEA(koff, p) do { \
    _Pragma("unroll") for (int i_ = 0; i_ < 4; ++i_) \
      GLDS(Ag + (size_t)(srow2 + i_ * 32) * K_ + (koff) + scw8, \
           &lds[p][(i_ * 256 + tid) * 8]); \
  } while (0)

#define READQ(p, mb) do { \
    _Pragma("unroll") for (int m_ = 0; m_ < 4; ++m_) \
    _Pragma("unroll") for (int ks_ = 0; ks_ < 2; ++ks_) \
      aq[m_][ks_] = *(const bf16x8*)(const void*)( \
          &lds[p][(size_t)((mb) + m_ * 16 + lrow) * 64 + \
                  (((ks_ * 4 + hi2) ^ sw) * 8)]); \
  } while (0)

#define MFMA32(base, bv) do { \
    __builtin_amdgcn_s_setprio(1); \
    _Pragma("unroll") for (int m_ = 0; m_ < 4; ++m_) \
    _Pragma("unroll") for (int n_ = 0; n_ < 4; ++n_) \
    _Pragma("unroll") for (int ks_ = 0; ks_ < 2; ++ks_) \
      acc[(base) + m_][n_] = __builtin_amdgcn_mfma_f32_16x16x32_bf16( \
          aq[m_][ks_], bv[n_][ks_], acc[(base) + m_][n_], 0, 0, 0); \
    __builtin_amdgcn_s_setprio(0); \
  } while (0)

  // ---- prologue: order fixes the vmcnt ledger: [B0:8][A0:4][B1:8][A1:4] ----
  LOADB(bE, 0);
  STAGEA(0, 0);
  LOADB(bO, BK);
  STAGEA(BK, 1);
  VMCNT(12);                 // B(0)+A(0) drained
  __builtin_amdgcn_s_barrier();
  MEMFENCE;
  READQ(0, 0);               // aq <- q0(tile 0)

  // ---- steady: 2 tiles per iter; i=0..30 covers tiles 0..61, prefetch ..63
  for (int i = 0; i < NT / 2 - 1; ++i) {
    const int ke = i * 2 * BK;           // even tile elem-offset
    // ===== even tile (bE, buf0) =====
    LGKM0;                               // aq q0 ready
    MFMA32(0, bE);
    READQ(0, 64);                        // aq <- q1 (WAR: after q0 MFMAs)
    LGKM0;
    MFMA32(4, bE);                       // bE dead after this
    LOADB(bE, ke + 2 * BK);              // B(t+2) -> bE   [8 vm]
    __builtin_amdgcn_s_barrier();        // all WG's buf0 reads served
    MEMFENCE;
    STAGEA(ke + 2 * BK, 0);              // A(t+2) -> buf0 [4 vm]
    VMCNT(12);                           // drains B(t+1)+A(t+1)
    __builtin_amdgcn_s_barrier();        // buf1 = A(t+1) visible WG-wide
    MEMFENCE;
    READQ(1, 0);                         // aq <- q0(t+1)
    // ===== odd tile (bO, buf1) =====
    LGKM0;
    MFMA32(0, bO);
    READQ(1, 64);
    LGKM0;
    MFMA32(4, bO);
    LOADB(bO, ke + 3 * BK);              // B(t+3) -> bO   [8 vm]
    __builtin_amdgcn_s_barrier();        // all WG's buf1 reads served
    MEMFENCE;
    STAGEA(ke + 3 * BK, 1);              // A(t+3) -> buf1 [4 vm]
    VMCNT(12);                           // drains B(t+2)+A(t+2)
    __builtin_amdgcn_s_barrier();        // buf0 = A(t+2) visible
    MEMFENCE;
    READQ(0, 0);                         // aq <- q0(t+2)
  }

  // ---- tail: tiles 62 (bE, buf0) and 63 (bO, buf1), no prefetch ----
  LGKM0;
  MFMA32(0, bE);
  READQ(0, 64);
  LGKM0;
  MFMA32(4, bE);
  VMCNT(0);                              // B(63)+A(63) drained
  __builtin_amdgcn_s_barrier();
  MEMFENCE;
  READQ(1, 0);
  LGKM0;
  MFMA32(0, bO);
  READQ(1, 64);
  LGKM0;
  MFMA32(4, bO);

  // ---- epilogue: C/D layout col = lane&15, row = (lane>>4)*4 + reg ----
  const int crow = brow + hi2 * 4;
  const int ccol = bcol + wn * 64 + lrow;
#pragma unroll
  for (int m = 0; m < 8; ++m)
#pragma unroll
    for (int n = 0; n < 4; ++n)
#pragma unroll
      for (int r = 0; r < 4; ++r)
        C[(size_t)(crow + m * 16 + r) * N_ + ccol + n * 16] = acc[m][n][r];
}

// ---------------------------------------------------------------------------
// Fallback (ws too small): fp32 tiled GEMM with on-the-fly dequant
// ---------------------------------------------------------------------------
__global__ __launch_bounds__(256) void fallback_kernel(
    const float* __restrict__ x, const float* __restrict__ cb,
    const float* __restrict__ scales, const int* __restrict__ idx,
    const int* __restrict__ signs, float* __restrict__ out)
{
  __shared__ float Xs[32][33];
  __shared__ float Ws[32][33];
  const int t = threadIdx.x;
  const int tx = t & 31, ty = t >> 5;
  const int brow = blockIdx.y * 32, bcol = blockIdx.x * 32;
  float acc[4] = {0.f, 0.f, 0.f, 0.f};

  for (int k0 = 0; k0 < K_; k0 += 32) {
    for (int l = t; l < 1024; l += 256) {
      const int r = l >> 5, c = l & 31;
      Xs[r][c] = x[(size_t)(brow + r) * K_ + k0 + c];
      const int n = bcol + r;
      const size_t flat = (size_t)n * K_ + (k0 + c);
      const int g = (int)(flat >> 3), j = (int)(flat & 7);
      float wv = cb[idx[g] * 8 + j] * scales[n];
      if (!((signs[g] >> (7 - j)) & 1)) wv = -wv;
      Ws[r][c] = wv;
    }
    __syncthreads();
#pragma unroll
    for (int kk = 0; kk < 32; ++kk) {
      const float wv = Ws[tx][kk];
      acc[0] += Xs[ty][kk] * wv;
      acc[1] += Xs[ty + 8][kk] * wv;
      acc[2] += Xs[ty + 16][kk] * wv;
      acc[3] += Xs[ty + 24][kk] * wv;
    }
    __syncthreads();
  }
#pragma unroll
  for (int q = 0; q < 4; ++q)
    out[(size_t)(brow + ty + 8 * q) * N_ + bcol + tx] = acc[q];
}

// ---------------------------------------------------------------------------
extern "C" void kernel_launch(void* const* d_in, const int* in_sizes, int n_in,
                              void* d_out, int out_size, void* d_ws, size_t ws_size,
                              hipStream_t stream)
{
  const float* x      = (const float*)d_in[0];
  const float* cb     = (const float*)d_in[1];
  const float* scales = (const float*)d_in[2];
  const int*   idx    = (const int*)d_in[3];
  const int*   signs  = (const int*)d_in[4];
  float* out = (float*)d_out;

  const size_t wbytes = (size_t)N_ * K_ * 2;
  const size_t xbytes = (size_t)M_ * K_ * 2;

  if (ws_size >= wbytes + xbytes) {
    unsigned short* Wb = (unsigned short*)d_ws;
    unsigned short* Xb = (unsigned short*)((char*)d_ws + wbytes);
    dequant_w_kernel<<<(N_ * K_ / 8) / 256, 256, 0, stream>>>(cb, scales, idx, signs, Wb);
    cvt_x_kernel<<<(M_ * K_ / 8) / 256, 256, 0, stream>>>(x, Xb);
    gemm128_kernel<<<(M_ / BM) * (N_ / BN), 256, 0, stream>>>(Xb, Wb, out);
  } else {
    fallback_kernel<<<dim3(N_ / 32, M_ / 32), 256, 0, stream>>>(x, cb, scales, idx, signs, out);
  }
}

// Round 8
// 279.499 us; speedup vs baseline: 1.2818x; 1.2818x over previous
//
#include <hip/hip_runtime.h>

// SymHQLinear: out[8192,4096] = x @ W^T; W[4096,4096] dequantized from
// codebook[4096,8] + per-row scales + packed sign bits.
#define M_ 8192   // TOKENS
#define N_ 4096   // OUT
#define K_ 4096   // IN

typedef __bf16 bf16x8 __attribute__((ext_vector_type(8)));
typedef float  f32x4  __attribute__((ext_vector_type(4)));

__device__ __forceinline__ unsigned short f2bf(float f) {
  unsigned u = __builtin_bit_cast(unsigned, f);
  unsigned r = 0x7fffu + ((u >> 16) & 1u);
  return (unsigned short)((u + r) >> 16);
}

// ---------------------------------------------------------------------------
// Kernel 1: dequantize W -> bf16 [N_][K_]
// ---------------------------------------------------------------------------
__global__ __launch_bounds__(256) void dequant_w_kernel(
    const float* __restrict__ cb, const float* __restrict__ scales,
    const int* __restrict__ idx, const int* __restrict__ signs,
    unsigned short* __restrict__ Wb)
{
  const int g   = blockIdx.x * 256 + threadIdx.x;
  const int row = g >> 9;
  const int code = idx[g];
  const int sb   = signs[g];
  const float s  = scales[row];
  const float* cv = cb + code * 8;

  unsigned short h[8];
#pragma unroll
  for (int j = 0; j < 8; ++j) {
    float v = cv[j] * s;
    if (!((sb >> (7 - j)) & 1)) v = -v;
    h[j] = f2bf(v);
  }
  uint4 o;
  o.x = (unsigned)h[0] | ((unsigned)h[1] << 16);
  o.y = (unsigned)h[2] | ((unsigned)h[3] << 16);
  o.z = (unsigned)h[4] | ((unsigned)h[5] << 16);
  o.w = (unsigned)h[6] | ((unsigned)h[7] << 16);
  *(uint4*)(Wb + (size_t)g * 8) = o;
}

// ---------------------------------------------------------------------------
// Kernel 2: cast x fp32 -> bf16
// ---------------------------------------------------------------------------
__global__ __launch_bounds__(256) void cvt_x_kernel(
    const float* __restrict__ x, unsigned short* __restrict__ Xb)
{
  const size_t i = (size_t)blockIdx.x * 256 + threadIdx.x;
  const f32x4* px = (const f32x4*)(x + i * 8);
  f32x4 a = px[0], b = px[1];
  uint4 o;
  o.x = (unsigned)f2bf(a[0]) | ((unsigned)f2bf(a[1]) << 16);
  o.y = (unsigned)f2bf(a[2]) | ((unsigned)f2bf(a[3]) << 16);
  o.z = (unsigned)f2bf(b[0]) | ((unsigned)f2bf(b[1]) << 16);
  o.w = (unsigned)f2bf(b[2]) | ((unsigned)f2bf(b[3]) << 16);
  *(uint4*)(Xb + i * 8) = o;
}

// ---------------------------------------------------------------------------
// Kernel 3: 256x256x64 GEMM, fine-grained 4-phase/tile (m201-style):
// every phase: {ds_reads(this phase) ; stage EXACTLY 2 GLDS ; [lgkm(8)] ;
// barrier ; lgkm(0) ; 16 MFMA ; vmcnt(8) ; barrier}.
// Stage rotation (uniform, 2 half-regions per phase):
//   q0: A0.hi,A1.hi (T+1)   [slots last read at (T)q... A-hi(T+1) slot was
//                            read at (T-1)q2 -> free]
//   q1: A0.lo,A1.lo (T+2)   [read at (T)q0 -> free]
//   q2: B0.lo,B0.hi (T+2)   [read q0+q1 -> free]
//   q3: B1.lo,B1.hi (T+2)   [read q0+q1 -> free]
// Uniform vmcnt(8) (keep 4 newest pairs) each phase-end: any half consumed
// at age >=5 phases is drained -- holds for steady, fill, and prologue.
// Tail: tile NT-2 ends with vmcnt(0); NT-1 stages nothing.
// ---------------------------------------------------------------------------
#define BM 256
#define BN 256
#define BK 64
#define NT (K_ / BK)          // 64 K-tiles

#define GLDS(g, l) __builtin_amdgcn_global_load_lds( \
    (const __attribute__((address_space(1))) void*)(g), \
    (__attribute__((address_space(3))) void*)(l), 16, 0, 0)

#define LGKM_WAIT(n) do { \
    asm volatile("s_waitcnt lgkmcnt(" #n ")" ::: "memory"); \
    __builtin_amdgcn_sched_barrier(0); \
  } while (0)

#define VM_WAIT(n) do { \
    asm volatile("s_waitcnt vmcnt(" #n ")" ::: "memory"); \
    __builtin_amdgcn_sched_barrier(0); \
  } while (0)

#define MEMFENCE asm volatile("" ::: "memory")

// frag read with 16B-chunk involution swizzle: chunk ^= (row & 7)
#define FRAG(base_ptr, rowexpr, kc) \
  (*(const bf16x8*)(const void*)((base_ptr) + (size_t)(rowexpr) * 64 + \
      ((((kc)) ^ ((rowexpr) & 7)) * 8)))

// MODE: 0 steady, 1 = T==NT-2 (only q0 stage; q3 ends vmcnt(0)), 2 = T==NT-1
template<int MODE>
__device__ __forceinline__ void tile_step(
    int T, unsigned short (*lds)[4][8192], f32x4 (&acc)[8][4],
    const unsigned short* __restrict__ Ag,
    const unsigned short* __restrict__ Bg,
    int wm, int wnl, int bsel, int lrow, int hi2,
    int tid, int srow, int scw8)
{
  const int b = T & 1, nb = b ^ 1;
  const unsigned short* Areg = &lds[b][wm][0];
  const unsigned short* Breg = &lds[b][2 + bsel][0];

  bf16x8 aq[4][2], bl[2][2], bh[2][2];

  // ================= q0: reads A-lo(8)+blo(4); stage A-hi(T+1) =============
#pragma unroll
  for (int m = 0; m < 4; ++m)
#pragma unroll
    for (int ks = 0; ks < 2; ++ks)
      aq[m][ks] = FRAG(Areg, m * 16 + lrow, ks * 4 + hi2);
#pragma unroll
  for (int n = 0; n < 2; ++n)
#pragma unroll
    for (int ks = 0; ks < 2; ++ks)
      bl[n][ks] = FRAG(Breg, wnl * 64 + n * 16 + lrow, ks * 4 + hi2);
  if (MODE <= 1) {
    GLDS(Ag + (size_t)(64 + srow) * K_ + (T + 1) * BK + scw8,  &lds[nb][0][4096 + tid * 8]);
    GLDS(Ag + (size_t)(192 + srow) * K_ + (T + 1) * BK + scw8, &lds[nb][1][4096 + tid * 8]);
  }
  LGKM_WAIT(8);
  __builtin_amdgcn_s_barrier();
  LGKM_WAIT(0);
  __builtin_amdgcn_s_setprio(1);
#pragma unroll
  for (int m = 0; m < 4; ++m)
#pragma unroll
    for (int n = 0; n < 2; ++n)
#pragma unroll
      for (int ks = 0; ks < 2; ++ks)
        acc[m][n] = __builtin_amdgcn_mfma_f32_16x16x32_bf16(aq[m][ks], bl[n][ks], acc[m][n], 0, 0, 0);
  __builtin_amdgcn_s_setprio(0);
  if (MODE < 2) VM_WAIT(8);
  __builtin_amdgcn_s_barrier();
  MEMFENCE;

  // ================= q1: reads bhi(4); stage A-lo(T+2) =====================
#pragma unroll
  for (int n = 0; n < 2; ++n)
#pragma unroll
    for (int ks = 0; ks < 2; ++ks)
      bh[n][ks] = FRAG(Breg, wnl * 64 + 32 + n * 16 + lrow, ks * 4 + hi2);
  if (MODE == 0) {
    GLDS(Ag + (size_t)(srow) * K_ + (T + 2) * BK + scw8,       &lds[b][0][tid * 8]);
    GLDS(Ag + (size_t)(128 + srow) * K_ + (T + 2) * BK + scw8, &lds[b][1][tid * 8]);
  }
  __builtin_amdgcn_s_barrier();
  LGKM_WAIT(0);
  __builtin_amdgcn_s_setprio(1);
#pragma unroll
  for (int m = 0; m < 4; ++m)
#pragma unroll
    for (int n = 0; n < 2; ++n)
#pragma unroll
      for (int ks = 0; ks < 2; ++ks)
        acc[m][2 + n] = __builtin_amdgcn_mfma_f32_16x16x32_bf16(aq[m][ks], bh[n][ks], acc[m][2 + n], 0, 0, 0);
  __builtin_amdgcn_s_setprio(0);
  if (MODE < 2) VM_WAIT(8);
  __builtin_amdgcn_s_barrier();
  MEMFENCE;

  // ================= q2: reads A-hi(8); stage B0(T+2) ======================
#pragma unroll
  for (int m = 0; m < 4; ++m)
#pragma unroll
    for (int ks = 0; ks < 2; ++ks)
      aq[m][ks] = FRAG(Areg, 64 + m * 16 + lrow, ks * 4 + hi2);
  if (MODE == 0) {
    GLDS(Bg + (size_t)(srow) * K_ + (T + 2) * BK + scw8,      &lds[b][2][tid * 8]);
    GLDS(Bg + (size_t)(64 + srow) * K_ + (T + 2) * BK + scw8, &lds[b][2][4096 + tid * 8]);
  }
  __builtin_amdgcn_s_barrier();
  LGKM_WAIT(0);
  __builtin_amdgcn_s_setprio(1);
#pragma unroll
  for (int m = 0; m < 4; ++m)
#pragma unroll
    for (int n = 0; n < 2; ++n)
#pragma unroll
      for (int ks = 0; ks < 2; ++ks)
        acc[4 + m][n] = __builtin_amdgcn_mfma_f32_16x16x32_bf16(aq[m][ks], bl[n][ks], acc[4 + m][n], 0, 0, 0);
  __builtin_amdgcn_s_setprio(0);
  if (MODE < 2) VM_WAIT(8);
  __builtin_amdgcn_s_barrier();
  MEMFENCE;

  // ================= q3: no reads; stage B1(T+2) ===========================
  if (MODE == 0) {
    GLDS(Bg + (size_t)(128 + srow) * K_ + (T + 2) * BK + scw8, &lds[b][3][tid * 8]);
    GLDS(Bg + (size_t)(192 + srow) * K_ + (T + 2) * BK + scw8, &lds[b][3][4096 + tid * 8]);
  }
  __builtin_amdgcn_s_barrier();
  __builtin_amdgcn_s_setprio(1);
#pragma unroll
  for (int m = 0; m < 4; ++m)
#pragma unroll
    for (int n = 0; n < 2; ++n)
#pragma unroll
      for (int ks = 0; ks < 2; ++ks)
        acc[4 + m][2 + n] = __builtin_amdgcn_mfma_f32_16x16x32_bf16(aq[m][ks], bh[n][ks], acc[4 + m][2 + n], 0, 0, 0);
  __builtin_amdgcn_s_setprio(0);
  if (MODE == 0)      VM_WAIT(8);
  else if (MODE == 1) VM_WAIT(0);     // full drain before the last tile
  __builtin_amdgcn_s_barrier();
  MEMFENCE;
}

__global__ __launch_bounds__(512, 2) void gemm256_kernel(
    const unsigned short* __restrict__ A,   // Xb [M_][K_]
    const unsigned short* __restrict__ B,   // Wb [N_][K_]
    float* __restrict__ C)
{
  __shared__ unsigned short lds[2][4][8192];    // 128 KiB

  // XCD-aware bijective swizzle (nwg = 512, 512 % 8 == 0)
  const int nwg = (M_ / BM) * (N_ / BN);
  const int bid = blockIdx.x;
  const int wg  = (bid % 8) * (nwg / 8) + bid / 8;
  const int tn  = wg % (N_ / BN);
  const int tm  = wg / (N_ / BN);
  const int brow = tm * BM, bcol = tn * BN;

  const int tid  = threadIdx.x;
  const int lane = tid & 63, w = tid >> 6;
  const int wm   = w >> 2, wn = w & 3;      // 2 (M) x 4 (N)
  const int wnl  = wn & 1, bsel = wn >> 1;
  const int lrow = lane & 15, hi2 = lane >> 4;
  const int srow = tid >> 3;                // staging row 0..63
  const int scw8 = ((tid & 7) ^ ((tid >> 3) & 7)) * 8;  // inv-swizzled col

  const unsigned short* Ag = A + (size_t)brow * K_;
  const unsigned short* Bg = B + (size_t)bcol * K_;

  f32x4 acc[8][4];
#pragma unroll
  for (int m = 0; m < 8; ++m)
#pragma unroll
    for (int n = 0; n < 4; ++n)
      acc[m][n] = f32x4{0.f, 0.f, 0.f, 0.f};

  // ---- prologue: 7 pairs, order = [Alo0][B0_0][B1_0][Ahi0][Alo1][B0_1][B1_1]
  GLDS(Ag + (size_t)(srow) * K_ + scw8,            &lds[0][0][tid * 8]);
  GLDS(Ag + (size_t)(128 + srow) * K_ + scw8,      &lds[0][1][tid * 8]);
  GLDS(Bg + (size_t)(srow) * K_ + scw8,            &lds[0][2][tid * 8]);
  GLDS(Bg + (size_t)(64 + srow) * K_ + scw8,       &lds[0][2][4096 + tid * 8]);
  GLDS(Bg + (size_t)(128 + srow) * K_ + scw8,      &lds[0][3][tid * 8]);
  GLDS(Bg + (size_t)(192 + srow) * K_ + scw8,      &lds[0][3][4096 + tid * 8]);
  GLDS(Ag + (size_t)(64 + srow) * K_ + scw8,       &lds[0][0][4096 + tid * 8]);
  GLDS(Ag + (size_t)(192 + srow) * K_ + scw8,      &lds[0][1][4096 + tid * 8]);
  GLDS(Ag + (size_t)(srow) * K_ + BK + scw8,       &lds[1][0][tid * 8]);
  GLDS(Ag + (size_t)(128 + srow) * K_ + BK + scw8, &lds[1][1][tid * 8]);
  GLDS(Bg + (size_t)(srow) * K_ + BK + scw8,       &lds[1][2][tid * 8]);
  GLDS(Bg + (size_t)(64 + srow) * K_ + BK + scw8,  &lds[1][2][4096 + tid * 8]);
  GLDS(Bg + (size_t)(128 + srow) * K_ + BK + scw8, &lds[1][3][tid * 8]);
  GLDS(Bg + (size_t)(192 + srow) * K_ + BK + scw8, &lds[1][3][4096 + tid * 8]);
  VM_WAIT(8);                  // drains pairs 1-3 = exactly what (0)q0 reads
  __builtin_amdgcn_s_barrier();
  MEMFENCE;

  for (int T = 0; T < NT - 2; ++T)
    tile_step<0>(T, lds, acc, Ag, Bg, wm, wnl, bsel, lrow, hi2, tid, srow, scw8);
  tile_step<1>(NT - 2, lds, acc, Ag, Bg, wm, wnl, bsel, lrow, hi2, tid, srow, scw8);
  tile_step<2>(NT - 1, lds, acc, Ag, Bg, wm, wnl, bsel, lrow, hi2, tid, srow, scw8);

  // epilogue: C/D layout col = lane&15, row = (lane>>4)*4 + reg
  const int crow = brow + wm * 128 + hi2 * 4;
  const int ccol = bcol + wn * 64 + lrow;
#pragma unroll
  for (int m = 0; m < 8; ++m)
#pragma unroll
    for (int n = 0; n < 4; ++n)
#pragma unroll
      for (int r = 0; r < 4; ++r)
        C[(size_t)(crow + m * 16 + r) * N_ + ccol + n * 16] = acc[m][n][r];
}

// ---------------------------------------------------------------------------
// Fallback (ws too small): fp32 tiled GEMM with on-the-fly dequant
// ---------------------------------------------------------------------------
__global__ __launch_bounds__(256) void fallback_kernel(
    const float* __restrict__ x, const float* __restrict__ cb,
    const float* __restrict__ scales, const int* __restrict__ idx,
    const int* __restrict__ signs, float* __restrict__ out)
{
  __shared__ float Xs[32][33];
  __shared__ float Ws[32][33];
  const int t = threadIdx.x;
  const int tx = t & 31, ty = t >> 5;
  const int brow = blockIdx.y * 32, bcol = blockIdx.x * 32;
  float acc[4] = {0.f, 0.f, 0.f, 0.f};

  for (int k0 = 0; k0 < K_; k0 += 32) {
    for (int l = t; l < 1024; l += 256) {
      const int r = l >> 5, c = l & 31;
      Xs[r][c] = x[(size_t)(brow + r) * K_ + k0 + c];
      const int n = bcol + r;
      const size_t flat = (size_t)n * K_ + (k0 + c);
      const int g = (int)(flat >> 3), j = (int)(flat & 7);
      float wv = cb[idx[g] * 8 + j] * scales[n];
      if (!((signs[g] >> (7 - j)) & 1)) wv = -wv;
      Ws[r][c] = wv;
    }
    __syncthreads();
#pragma unroll
    for (int kk = 0; kk < 32; ++kk) {
      const float wv = Ws[tx][kk];
      acc[0] += Xs[ty][kk] * wv;
      acc[1] += Xs[ty + 8][kk] * wv;
      acc[2] += Xs[ty + 16][kk] * wv;
      acc[3] += Xs[ty + 24][kk] * wv;
    }
    __syncthreads();
  }
#pragma unroll
  for (int q = 0; q < 4; ++q)
    out[(size_t)(brow + ty + 8 * q) * N_ + bcol + tx] = acc[q];
}

// ---------------------------------------------------------------------------
extern "C" void kernel_launch(void* const* d_in, const int* in_sizes, int n_in,
                              void* d_out, int out_size, void* d_ws, size_t ws_size,
                              hipStream_t stream)
{
  const float* x      = (const float*)d_in[0];
  const float* cb     = (const float*)d_in[1];
  const float* scales = (const float*)d_in[2];
  const int*   idx    = (const int*)d_in[3];
  const int*   signs  = (const int*)d_in[4];
  float* out = (float*)d_out;

  const size_t wbytes = (size_t)N_ * K_ * 2;
  const size_t xbytes = (size_t)M_ * K_ * 2;

  if (ws_size >= wbytes + xbytes) {
    unsigned short* Wb = (unsigned short*)d_ws;
    unsigned short* Xb = (unsigned short*)((char*)d_ws + wbytes);
    dequant_w_kernel<<<(N_ * K_ / 8) / 256, 256, 0, stream>>>(cb, scales, idx, signs, Wb);
    cvt_x_kernel<<<(M_ * K_ / 8) / 256, 256, 0, stream>>>(x, Xb);
    gemm256_kernel<<<(M_ / BM) * (N_ / BN), 512, 0, stream>>>(Xb, Wb, out);
  } else {
    fallback_kernel<<<dim3(N_ / 32, M_ / 32), 256, 0, stream>>>(x, cb, scales, idx, signs, out);
  }
}

// Round 9
// 276.649 us; speedup vs baseline: 1.2950x; 1.0103x over previous
//
#include <hip/hip_runtime.h>

// SymHQLinear: out[8192,4096] = x @ W^T; W[4096,4096] dequantized from
// codebook[4096,8] + per-row scales + packed sign bits.
#define M_ 8192   // TOKENS
#define N_ 4096   // OUT
#define K_ 4096   // IN

typedef __bf16 bf16x8 __attribute__((ext_vector_type(8)));
typedef float  f32x4  __attribute__((ext_vector_type(4)));

__device__ __forceinline__ unsigned short f2bf(float f) {
  unsigned u = __builtin_bit_cast(unsigned, f);
  unsigned r = 0x7fffu + ((u >> 16) & 1u);
  return (unsigned short)((u + r) >> 16);
}

// ---------------------------------------------------------------------------
// Kernel 1 (fused): blocks [0, 8192) dequantize W -> bf16 [N_][K_];
//                   blocks [8192, 24576) cast x fp32 -> bf16.
// ---------------------------------------------------------------------------
__global__ __launch_bounds__(256) void prep_kernel(
    const float* __restrict__ x, const float* __restrict__ cb,
    const float* __restrict__ scales, const int* __restrict__ idx,
    const int* __restrict__ signs,
    unsigned short* __restrict__ Wb, unsigned short* __restrict__ Xb)
{
  const int b = blockIdx.x;
  if (b < (N_ * K_ / 8) / 256) {
    const int g   = b * 256 + threadIdx.x;
    const int row = g >> 9;                         // 512 groups per row
    const int code = idx[g];
    const int sb   = signs[g];
    const float s  = scales[row];
    const float* cv = cb + code * 8;
    unsigned short h[8];
#pragma unroll
    for (int j = 0; j < 8; ++j) {
      float v = cv[j] * s;
      if (!((sb >> (7 - j)) & 1)) v = -v;
      h[j] = f2bf(v);
    }
    uint4 o;
    o.x = (unsigned)h[0] | ((unsigned)h[1] << 16);
    o.y = (unsigned)h[2] | ((unsigned)h[3] << 16);
    o.z = (unsigned)h[4] | ((unsigned)h[5] << 16);
    o.w = (unsigned)h[6] | ((unsigned)h[7] << 16);
    *(uint4*)(Wb + (size_t)g * 8) = o;
  } else {
    const size_t i = (size_t)(b - (N_ * K_ / 8) / 256) * 256 + threadIdx.x;
    const f32x4* px = (const f32x4*)(x + i * 8);
    f32x4 a = px[0], c = px[1];
    uint4 o;
    o.x = (unsigned)f2bf(a[0]) | ((unsigned)f2bf(a[1]) << 16);
    o.y = (unsigned)f2bf(a[2]) | ((unsigned)f2bf(a[3]) << 16);
    o.z = (unsigned)f2bf(c[0]) | ((unsigned)f2bf(c[1]) << 16);
    o.w = (unsigned)f2bf(c[2]) | ((unsigned)f2bf(c[3]) << 16);
    *(uint4*)(Xb + i * 8) = o;
  }
}

// ---------------------------------------------------------------------------
// Kernel 2: 256x256x64 GEMM, fine-grained 4-phase/tile, SINGLE vmcnt(6) per
// K-tile (m201 T4-exact).  Phases (per tile T, buf b=T&1, next nb):
//   q0: reads A-lo(8)+B-lo(4); stage A-hi(T+1)->nb ; lgkm(8); bar; lgkm0; MFMA
//   q1: reads B-hi(4);        stage A-lo(T+2)->b  ; bar; lgkm0; MFMA
//   q2: reads A-hi(8);        stage B-lo(T+2)->b  ; bar; lgkm0; MFMA
//   q3: no reads;             stage B-hi(T+2)->b  ; bar; MFMA; vmcnt(6); bar
// vmcnt ledger @ T q3 (oldest first): [T-1 q1q2q3 = T+1 data, 6][T q0 =
// A-hi(T+1), 2][T q1q2q3 = T+2 data, 6] = 14 -> keep 6 drains ALL T+1 data.
// Prologue ends vmcnt(6) (drains tile-0's 8 exactly). T=NT-2: stage q0 only,
// ends vmcnt(0). T=NT-1: nothing.
// WAR on LDS slots is vmcnt-independent: each slot staged only after its
// last reader's lgkm(0) + phase-end barrier (unchanged from R8).
// ---------------------------------------------------------------------------
#define BM 256
#define BN 256
#define BK 64
#define NT (K_ / BK)          // 64 K-tiles

#define GLDS(g, l) __builtin_amdgcn_global_load_lds( \
    (const __attribute__((address_space(1))) void*)(g), \
    (__attribute__((address_space(3))) void*)(l), 16, 0, 0)

#define LGKM_WAIT(n) do { \
    asm volatile("s_waitcnt lgkmcnt(" #n ")" ::: "memory"); \
    __builtin_amdgcn_sched_barrier(0); \
  } while (0)

#define VM_WAIT(n) asm volatile("s_waitcnt vmcnt(" #n ")" ::: "memory")

#define MEMFENCE asm volatile("" ::: "memory")

// frag read with 16B-chunk involution swizzle: chunk ^= (row & 7)
#define FRAG(base_ptr, rowexpr, kc) \
  (*(const bf16x8*)(const void*)((base_ptr) + (size_t)(rowexpr) * 64 + \
      ((((kc)) ^ ((rowexpr) & 7)) * 8)))

// MODE: 0 steady, 1 = T==NT-2 (q0 stage only; q3 ends vmcnt(0)), 2 = T==NT-1
template<int MODE>
__device__ __forceinline__ void tile_step(
    int T, unsigned short (*lds)[4][8192], f32x4 (&acc)[8][4],
    const unsigned short* __restrict__ Ag,
    const unsigned short* __restrict__ Bg,
    int wm, int wnl, int bsel, int lrow, int hi2,
    int tid, int srow, int scw8)
{
  const int b = T & 1, nb = b ^ 1;
  const unsigned short* Areg = &lds[b][wm][0];
  const unsigned short* Breg = &lds[b][2 + bsel][0];

  bf16x8 aq[4][2], bl[2][2], bh[2][2];

  // ================= q0: reads A-lo(8)+blo(4); stage A-hi(T+1) =============
#pragma unroll
  for (int m = 0; m < 4; ++m)
#pragma unroll
    for (int ks = 0; ks < 2; ++ks)
      aq[m][ks] = FRAG(Areg, m * 16 + lrow, ks * 4 + hi2);
#pragma unroll
  for (int n = 0; n < 2; ++n)
#pragma unroll
    for (int ks = 0; ks < 2; ++ks)
      bl[n][ks] = FRAG(Breg, wnl * 64 + n * 16 + lrow, ks * 4 + hi2);
  if (MODE <= 1) {
    GLDS(Ag + (size_t)(64 + srow) * K_ + (T + 1) * BK + scw8,  &lds[nb][0][4096 + tid * 8]);
    GLDS(Ag + (size_t)(192 + srow) * K_ + (T + 1) * BK + scw8, &lds[nb][1][4096 + tid * 8]);
  }
  LGKM_WAIT(8);
  __builtin_amdgcn_s_barrier();
  LGKM_WAIT(0);
  __builtin_amdgcn_s_setprio(1);
#pragma unroll
  for (int m = 0; m < 4; ++m)
#pragma unroll
    for (int n = 0; n < 2; ++n)
#pragma unroll
      for (int ks = 0; ks < 2; ++ks)
        acc[m][n] = __builtin_amdgcn_mfma_f32_16x16x32_bf16(aq[m][ks], bl[n][ks], acc[m][n], 0, 0, 0);
  __builtin_amdgcn_s_setprio(0);
  __builtin_amdgcn_s_barrier();
  MEMFENCE;

  // ================= q1: reads bhi(4); stage A-lo(T+2) =====================
#pragma unroll
  for (int n = 0; n < 2; ++n)
#pragma unroll
    for (int ks = 0; ks < 2; ++ks)
      bh[n][ks] = FRAG(Breg, wnl * 64 + 32 + n * 16 + lrow, ks * 4 + hi2);
  if (MODE == 0) {
    GLDS(Ag + (size_t)(srow) * K_ + (T + 2) * BK + scw8,       &lds[b][0][tid * 8]);
    GLDS(Ag + (size_t)(128 + srow) * K_ + (T + 2) * BK + scw8, &lds[b][1][tid * 8]);
  }
  __builtin_amdgcn_s_barrier();
  LGKM_WAIT(0);
  __builtin_amdgcn_s_setprio(1);
#pragma unroll
  for (int m = 0; m < 4; ++m)
#pragma unroll
    for (int n = 0; n < 2; ++n)
#pragma unroll
      for (int ks = 0; ks < 2; ++ks)
        acc[m][2 + n] = __builtin_amdgcn_mfma_f32_16x16x32_bf16(aq[m][ks], bh[n][ks], acc[m][2 + n], 0, 0, 0);
  __builtin_amdgcn_s_setprio(0);
  __builtin_amdgcn_s_barrier();
  MEMFENCE;

  // ================= q2: reads A-hi(8); stage B0(T+2) ======================
#pragma unroll
  for (int m = 0; m < 4; ++m)
#pragma unroll
    for (int ks = 0; ks < 2; ++ks)
      aq[m][ks] = FRAG(Areg, 64 + m * 16 + lrow, ks * 4 + hi2);
  if (MODE == 0) {
    GLDS(Bg + (size_t)(srow) * K_ + (T + 2) * BK + scw8,      &lds[b][2][tid * 8]);
    GLDS(Bg + (size_t)(64 + srow) * K_ + (T + 2) * BK + scw8, &lds[b][2][4096 + tid * 8]);
  }
  __builtin_amdgcn_s_barrier();
  LGKM_WAIT(0);
  __builtin_amdgcn_s_setprio(1);
#pragma unroll
  for (int m = 0; m < 4; ++m)
#pragma unroll
    for (int n = 0; n < 2; ++n)
#pragma unroll
      for (int ks = 0; ks < 2; ++ks)
        acc[4 + m][n] = __builtin_amdgcn_mfma_f32_16x16x32_bf16(aq[m][ks], bl[n][ks], acc[4 + m][n], 0, 0, 0);
  __builtin_amdgcn_s_setprio(0);
  __builtin_amdgcn_s_barrier();
  MEMFENCE;

  // ================= q3: no reads; stage B1(T+2); single vmcnt =============
  if (MODE == 0) {
    GLDS(Bg + (size_t)(128 + srow) * K_ + (T + 2) * BK + scw8, &lds[b][3][tid * 8]);
    GLDS(Bg + (size_t)(192 + srow) * K_ + (T + 2) * BK + scw8, &lds[b][3][4096 + tid * 8]);
  }
  __builtin_amdgcn_s_barrier();
  __builtin_amdgcn_s_setprio(1);
#pragma unroll
  for (int m = 0; m < 4; ++m)
#pragma unroll
    for (int n = 0; n < 2; ++n)
#pragma unroll
      for (int ks = 0; ks < 2; ++ks)
        acc[4 + m][2 + n] = __builtin_amdgcn_mfma_f32_16x16x32_bf16(aq[m][ks], bh[n][ks], acc[4 + m][2 + n], 0, 0, 0);
  __builtin_amdgcn_s_setprio(0);
  if (MODE == 0)      VM_WAIT(6);     // drains ALL tile-(T+1) data (ledger)
  else if (MODE == 1) VM_WAIT(0);     // full drain before the last tile
  __builtin_amdgcn_s_barrier();
  MEMFENCE;
}

__global__ __launch_bounds__(512, 2) void gemm256_kernel(
    const unsigned short* __restrict__ A,   // Xb [M_][K_]
    const unsigned short* __restrict__ B,   // Wb [N_][K_]
    float* __restrict__ C)
{
  __shared__ unsigned short lds[2][4][8192];    // 128 KiB

  // XCD-aware bijective swizzle (nwg = 512, 512 % 8 == 0)
  const int nwg = (M_ / BM) * (N_ / BN);
  const int bid = blockIdx.x;
  const int wg  = (bid % 8) * (nwg / 8) + bid / 8;
  const int tn  = wg % (N_ / BN);
  const int tm  = wg / (N_ / BN);
  const int brow = tm * BM, bcol = tn * BN;

  const int tid  = threadIdx.x;
  const int lane = tid & 63, w = tid >> 6;
  const int wm   = w >> 2, wn = w & 3;      // 2 (M) x 4 (N)
  const int wnl  = wn & 1, bsel = wn >> 1;
  const int lrow = lane & 15, hi2 = lane >> 4;
  const int srow = tid >> 3;                // staging row 0..63
  const int scw8 = ((tid & 7) ^ ((tid >> 3) & 7)) * 8;  // inv-swizzled col

  const unsigned short* Ag = A + (size_t)brow * K_;
  const unsigned short* Bg = B + (size_t)bcol * K_;

  f32x4 acc[8][4];
#pragma unroll
  for (int m = 0; m < 8; ++m)
#pragma unroll
    for (int n = 0; n < 4; ++n)
      acc[m][n] = f32x4{0.f, 0.f, 0.f, 0.f};

  // ---- prologue: tile0 complete (8 lines) then tile1 partial (6 lines) ----
  GLDS(Ag + (size_t)(srow) * K_ + scw8,            &lds[0][0][tid * 8]);
  GLDS(Ag + (size_t)(128 + srow) * K_ + scw8,      &lds[0][1][tid * 8]);
  GLDS(Bg + (size_t)(srow) * K_ + scw8,            &lds[0][2][tid * 8]);
  GLDS(Bg + (size_t)(64 + srow) * K_ + scw8,       &lds[0][2][4096 + tid * 8]);
  GLDS(Bg + (size_t)(128 + srow) * K_ + scw8,      &lds[0][3][tid * 8]);
  GLDS(Bg + (size_t)(192 + srow) * K_ + scw8,      &lds[0][3][4096 + tid * 8]);
  GLDS(Ag + (size_t)(64 + srow) * K_ + scw8,       &lds[0][0][4096 + tid * 8]);
  GLDS(Ag + (size_t)(192 + srow) * K_ + scw8,      &lds[0][1][4096 + tid * 8]);
  GLDS(Ag + (size_t)(srow) * K_ + BK + scw8,       &lds[1][0][tid * 8]);
  GLDS(Ag + (size_t)(128 + srow) * K_ + BK + scw8, &lds[1][1][tid * 8]);
  GLDS(Bg + (size_t)(srow) * K_ + BK + scw8,       &lds[1][2][tid * 8]);
  GLDS(Bg + (size_t)(64 + srow) * K_ + BK + scw8,  &lds[1][2][4096 + tid * 8]);
  GLDS(Bg + (size_t)(128 + srow) * K_ + BK + scw8, &lds[1][3][tid * 8]);
  GLDS(Bg + (size_t)(192 + srow) * K_ + BK + scw8, &lds[1][3][4096 + tid * 8]);
  VM_WAIT(6);                  // drains tile-0's 8 lines exactly
  __builtin_amdgcn_s_barrier();
  MEMFENCE;

  for (int T = 0; T < NT - 2; ++T)
    tile_step<0>(T, lds, acc, Ag, Bg, wm, wnl, bsel, lrow, hi2, tid, srow, scw8);
  tile_step<1>(NT - 2, lds, acc, Ag, Bg, wm, wnl, bsel, lrow, hi2, tid, srow, scw8);
  tile_step<2>(NT - 1, lds, acc, Ag, Bg, wm, wnl, bsel, lrow, hi2, tid, srow, scw8);

  // epilogue: C/D layout col = lane&15, row = (lane>>4)*4 + reg
  const int crow = brow + wm * 128 + hi2 * 4;
  const int ccol = bcol + wn * 64 + lrow;
#pragma unroll
  for (int m = 0; m < 8; ++m)
#pragma unroll
    for (int n = 0; n < 4; ++n)
#pragma unroll
      for (int r = 0; r < 4; ++r)
        C[(size_t)(crow + m * 16 + r) * N_ + ccol + n * 16] = acc[m][n][r];
}

// ---------------------------------------------------------------------------
// Fallback (ws too small): fp32 tiled GEMM with on-the-fly dequant
// ---------------------------------------------------------------------------
__global__ __launch_bounds__(256) void fallback_kernel(
    const float* __restrict__ x, const float* __restrict__ cb,
    const float* __restrict__ scales, const int* __restrict__ idx,
    const int* __restrict__ signs, float* __restrict__ out)
{
  __shared__ float Xs[32][33];
  __shared__ float Ws[32][33];
  const int t = threadIdx.x;
  const int tx = t & 31, ty = t >> 5;
  const int brow = blockIdx.y * 32, bcol = blockIdx.x * 32;
  float acc[4] = {0.f, 0.f, 0.f, 0.f};

  for (int k0 = 0; k0 < K_; k0 += 32) {
    for (int l = t; l < 1024; l += 256) {
      const int r = l >> 5, c = l & 31;
      Xs[r][c] = x[(size_t)(brow + r) * K_ + k0 + c];
      const int n = bcol + r;
      const size_t flat = (size_t)n * K_ + (k0 + c);
      const int g = (int)(flat >> 3), j = (int)(flat & 7);
      float wv = cb[idx[g] * 8 + j] * scales[n];
      if (!((signs[g] >> (7 - j)) & 1)) wv = -wv;
      Ws[r][c] = wv;
    }
    __syncthreads();
#pragma unroll
    for (int kk = 0; kk < 32; ++kk) {
      const float wv = Ws[tx][kk];
      acc[0] += Xs[ty][kk] * wv;
      acc[1] += Xs[ty + 8][kk] * wv;
      acc[2] += Xs[ty + 16][kk] * wv;
      acc[3] += Xs[ty + 24][kk] * wv;
    }
    __syncthreads();
  }
#pragma unroll
  for (int q = 0; q < 4; ++q)
    out[(size_t)(brow + ty + 8 * q) * N_ + bcol + tx] = acc[q];
}

// ---------------------------------------------------------------------------
extern "C" void kernel_launch(void* const* d_in, const int* in_sizes, int n_in,
                              void* d_out, int out_size, void* d_ws, size_t ws_size,
                              hipStream_t stream)
{
  const float* x      = (const float*)d_in[0];
  const float* cb     = (const float*)d_in[1];
  const float* scales = (const float*)d_in[2];
  const int*   idx    = (const int*)d_in[3];
  const int*   signs  = (const int*)d_in[4];
  float* out = (float*)d_out;

  const size_t wbytes = (size_t)N_ * K_ * 2;
  const size_t xbytes = (size_t)M_ * K_ * 2;

  if (ws_size >= wbytes + xbytes) {
    unsigned short* Wb = (unsigned short*)d_ws;
    unsigned short* Xb = (unsigned short*)((char*)d_ws + wbytes);
    const int nprep = (N_ * K_ / 8) / 256 + (M_ * K_ / 8) / 256;
    prep_kernel<<<nprep, 256, 0, stream>>>(x, cb, scales, idx, signs, Wb, Xb);
    gemm256_kernel<<<(M_ / BM) * (N_ / BN), 512, 0, stream>>>(Xb, Wb, out);
  } else {
    fallback_kernel<<<dim3(N_ / 32, M_ / 32), 256, 0, stream>>>(x, cb, scales, idx, signs, out);
  }
}

// Round 10
// 190.094 us; speedup vs baseline: 1.8847x; 1.4553x over previous
//
#include <hip/hip_runtime.h>

// SymHQLinear: out[8192,4096] = x @ W^T; W[4096,4096] dequantized from
// codebook[4096,8] + per-row scales + packed sign bits.
// Strategy: per-row symmetric i8 quantization of X and W (error << threshold),
// mfma_i32_16x16x64_i8 GEMM (2x K per instr: halves MFMA-pipe time, LDS
// traffic, and staging vs bf16), scales applied in the fp32 epilogue.
#define M_ 8192   // TOKENS
#define N_ 4096   // OUT
#define K_ 4096   // IN

typedef float f32x4 __attribute__((ext_vector_type(4)));
typedef int   i32x4 __attribute__((ext_vector_type(4)));

// ---------------------------------------------------------------------------
// Kernel 1 (fused prep): blocks [0, 4096): W row -> dequant, row-max, i8 + sw
//                        blocks [4096, 12288): X row -> row-max, i8 + sx
// ---------------------------------------------------------------------------
__device__ __forceinline__ unsigned pack4(const float* v, float inv) {
  unsigned r = 0;
#pragma unroll
  for (int j = 0; j < 4; ++j) {
    int q = (int)rintf(v[j] * inv);
    q = q < -127 ? -127 : (q > 127 ? 127 : q);
    r |= ((unsigned)(q & 0xff)) << (8 * j);
  }
  return r;
}

__global__ __launch_bounds__(256) void prep_kernel(
    const float* __restrict__ x, const float* __restrict__ cb,
    const float* __restrict__ scales, const int* __restrict__ idx,
    const int* __restrict__ signs,
    signed char* __restrict__ Wq, signed char* __restrict__ Xq,
    float* __restrict__ sw, float* __restrict__ sx)
{
  __shared__ float wred[4];
  const int b = blockIdx.x, t = threadIdx.x;

  if (b < N_) {
    // ---- W row b: 512 groups; thread handles groups t and t+256 ----
    const float s = scales[b];
    const int g0 = b * 512 + t, g1 = g0 + 256;
    const int c0 = idx[g0], c1 = idx[g1];
    const int sb0 = signs[g0], sb1 = signs[g1];
    const float* cv0 = cb + c0 * 8;
    const float* cv1 = cb + c1 * 8;
    float v[16];
    float mx = 0.f;
#pragma unroll
    for (int j = 0; j < 8; ++j) {
      float a = cv0[j] * s;
      if (!((sb0 >> (7 - j)) & 1)) a = -a;
      v[j] = a; mx = fmaxf(mx, fabsf(a));
    }
#pragma unroll
    for (int j = 0; j < 8; ++j) {
      float a = cv1[j] * s;
      if (!((sb1 >> (7 - j)) & 1)) a = -a;
      v[8 + j] = a; mx = fmaxf(mx, fabsf(a));
    }
#pragma unroll
    for (int off = 1; off < 64; off <<= 1) mx = fmaxf(mx, __shfl_xor(mx, off));
    if ((t & 63) == 0) wred[t >> 6] = mx;
    __syncthreads();
    mx = fmaxf(fmaxf(wred[0], wred[1]), fmaxf(wred[2], wred[3]));
    mx = fmaxf(mx, 1e-20f);
    const float inv = 127.0f / mx;
    if (t == 0) sw[b] = mx / 127.0f;
    uint2 o0 = {pack4(v, inv),     pack4(v + 4, inv)};
    uint2 o1 = {pack4(v + 8, inv), pack4(v + 12, inv)};
    *(uint2*)(Wq + (size_t)b * K_ + t * 8)        = o0;
    *(uint2*)(Wq + (size_t)b * K_ + 2048 + t * 8) = o1;
  } else {
    // ---- X row r: 4096 elems; thread handles 16 ----
    const int r = b - N_;
    const f32x4* px = (const f32x4*)(x + (size_t)r * K_ + t * 16);
    f32x4 a0 = px[0], a1 = px[1], a2 = px[2], a3 = px[3];
    float v[16];
#pragma unroll
    for (int j = 0; j < 4; ++j) { v[j] = a0[j]; v[4 + j] = a1[j]; v[8 + j] = a2[j]; v[12 + j] = a3[j]; }
    float mx = 0.f;
#pragma unroll
    for (int j = 0; j < 16; ++j) mx = fmaxf(mx, fabsf(v[j]));
#pragma unroll
    for (int off = 1; off < 64; off <<= 1) mx = fmaxf(mx, __shfl_xor(mx, off));
    if ((t & 63) == 0) wred[t >> 6] = mx;
    __syncthreads();
    mx = fmaxf(fmaxf(wred[0], wred[1]), fmaxf(wred[2], wred[3]));
    mx = fmaxf(mx, 1e-20f);
    const float inv = 127.0f / mx;
    if (t == 0) sx[r] = mx / 127.0f;
    uint4 o = {pack4(v, inv), pack4(v + 4, inv), pack4(v + 8, inv), pack4(v + 12, inv)};
    *(uint4*)(Xq + (size_t)r * K_ + t * 16) = o;
  }
}

// ---------------------------------------------------------------------------
// Kernel 2: 256x256x64 i8 GEMM, 2 phases/tile, mfma_i32_16x16x64_i8.
// LDS 64 KiB: [2 bufs][A|B][256 x 64 i8].  Rows are 64B -> the natural read
// pattern (row = lane&15, 16B chunk = lane>>4) is bank-conflict-free with NO
// swizzle (8 lanes per 4-bank group, balanced).  Staging: 2 GLDS per phase.
//   P0: read A-lo(4)+B(4); stage A(T+1)->nb ; BAR; lgkm0; 16 MFMA; BAR
//   P1: read A-hi(4);      stage B(T+2)->b  ; BAR; lgkm0; 16 MFMA; vmcnt(2); BAR
// WAR audit: A-slot[nb] last read tile T-1 P1 (lgkm0 + exit BAR) -> T P0 stage
// safe. B-slot[b] fully read in T P0 (lgkm0 + exit BAR) -> T P1 stage safe.
// vmcnt @ T P1-end: oldest [B(T+1):2][A(T+1):2][B(T+2):2] -> keep 2 drains
// all tile-(T+1) data.  Prologue: [A0:2][B0:2][B1:2], vmcnt(2) drains tile 0.
// T=NT-2: stage A(NT-1) only, ends vmcnt(0).  T=NT-1: no stage.
// ---------------------------------------------------------------------------
#define BM 256
#define BN 256
#define BK 64
#define NT (K_ / BK)          // 64 K-tiles

#define GLDS(g, l) __builtin_amdgcn_global_load_lds( \
    (const __attribute__((address_space(1))) void*)(g), \
    (__attribute__((address_space(3))) void*)(l), 16, 0, 0)

#define LGKM0 do { \
    asm volatile("s_waitcnt lgkmcnt(0)" ::: "memory"); \
    __builtin_amdgcn_sched_barrier(0); \
  } while (0)

#define VM_WAIT(n) asm volatile("s_waitcnt vmcnt(" #n ")" ::: "memory")
#define MEMFENCE asm volatile("" ::: "memory")

// MODE: 0 steady, 1 = T==NT-2, 2 = T==NT-1
template<int MODE>
__device__ __forceinline__ void tile_step(
    int T, signed char (*lds)[2][16384], i32x4 (&acc)[8][4],
    const signed char* __restrict__ Ag,
    const signed char* __restrict__ Bg,
    int wm, int wn, int lrow, int hi2, int tid)
{
  const int b = T & 1, nb = b ^ 1;
  const int sr = tid >> 2, sc = (tid & 3) * 16;   // staging row/col
  i32x4 av[4], bv[4];

  // ================= P0: read A-lo(4)+B(4); stage A(T+1) =================
#pragma unroll
  for (int m = 0; m < 4; ++m)
    av[m] = *(const i32x4*)(const void*)(
        &lds[b][0][(wm * 128 + m * 16 + lrow) * 64 + hi2 * 16]);
#pragma unroll
  for (int n = 0; n < 4; ++n)
    bv[n] = *(const i32x4*)(const void*)(
        &lds[b][1][(wn * 64 + n * 16 + lrow) * 64 + hi2 * 16]);
  if (MODE <= 1) {
    GLDS(Ag + (size_t)(sr) * K_ + (T + 1) * BK + sc,       &lds[nb][0][tid * 16]);
    GLDS(Ag + (size_t)(128 + sr) * K_ + (T + 1) * BK + sc, &lds[nb][0][8192 + tid * 16]);
  }
  __builtin_amdgcn_s_barrier();
  LGKM0;
  __builtin_amdgcn_s_setprio(1);
#pragma unroll
  for (int n = 0; n < 4; ++n)
#pragma unroll
    for (int m = 0; m < 4; ++m)
      acc[m][n] = __builtin_amdgcn_mfma_i32_16x16x64_i8(av[m], bv[n], acc[m][n], 0, 0, 0);
  __builtin_amdgcn_s_setprio(0);
  __builtin_amdgcn_s_barrier();
  MEMFENCE;

  // ================= P1: read A-hi(4); stage B(T+2); vmcnt ================
#pragma unroll
  for (int m = 0; m < 4; ++m)
    av[m] = *(const i32x4*)(const void*)(
        &lds[b][0][(wm * 128 + 64 + m * 16 + lrow) * 64 + hi2 * 16]);
  if (MODE == 0) {
    GLDS(Bg + (size_t)(sr) * K_ + (T + 2) * BK + sc,       &lds[b][1][tid * 16]);
    GLDS(Bg + (size_t)(128 + sr) * K_ + (T + 2) * BK + sc, &lds[b][1][8192 + tid * 16]);
  }
  __builtin_amdgcn_s_barrier();
  LGKM0;
  __builtin_amdgcn_s_setprio(1);
#pragma unroll
  for (int n = 0; n < 4; ++n)
#pragma unroll
    for (int m = 0; m < 4; ++m)
      acc[4 + m][n] = __builtin_amdgcn_mfma_i32_16x16x64_i8(av[m], bv[n], acc[4 + m][n], 0, 0, 0);
  __builtin_amdgcn_s_setprio(0);
  if (MODE == 0)      VM_WAIT(2);     // drains all tile-(T+1) data (ledger)
  else if (MODE == 1) VM_WAIT(0);     // drains A(NT-1), B(NT-1)
  __builtin_amdgcn_s_barrier();
  MEMFENCE;
}

__global__ __launch_bounds__(512, 2) void gemmq_kernel(
    const signed char* __restrict__ A,   // Xq [M_][K_] i8
    const signed char* __restrict__ B,   // Wq [N_][K_] i8
    const float* __restrict__ sx, const float* __restrict__ sw,
    float* __restrict__ C)
{
  __shared__ signed char lds[2][2][16384];  // 64 KiB

  // XCD-aware bijective swizzle (nwg = 512, 512 % 8 == 0)
  const int nwg = (M_ / BM) * (N_ / BN);
  const int bid = blockIdx.x;
  const int wg  = (bid % 8) * (nwg / 8) + bid / 8;
  const int tn  = wg % (N_ / BN);
  const int tm  = wg / (N_ / BN);
  const int brow = tm * BM, bcol = tn * BN;

  const int tid  = threadIdx.x;
  const int lane = tid & 63, w = tid >> 6;
  const int wm   = w >> 2, wn = w & 3;      // 2 (M) x 4 (N)
  const int lrow = lane & 15, hi2 = lane >> 4;
  const int sr = tid >> 2, sc = (tid & 3) * 16;

  const signed char* Ag = A + (size_t)brow * K_;
  const signed char* Bg = B + (size_t)bcol * K_;

  i32x4 acc[8][4];
#pragma unroll
  for (int m = 0; m < 8; ++m)
#pragma unroll
    for (int n = 0; n < 4; ++n)
      acc[m][n] = i32x4{0, 0, 0, 0};

  // ---- prologue: [A(0):2][B(0):2][B(1):2]; vmcnt(2) drains tile 0 ----
  GLDS(Ag + (size_t)(sr) * K_ + sc,            &lds[0][0][tid * 16]);
  GLDS(Ag + (size_t)(128 + sr) * K_ + sc,      &lds[0][0][8192 + tid * 16]);
  GLDS(Bg + (size_t)(sr) * K_ + sc,            &lds[0][1][tid * 16]);
  GLDS(Bg + (size_t)(128 + sr) * K_ + sc,      &lds[0][1][8192 + tid * 16]);
  GLDS(Bg + (size_t)(sr) * K_ + BK + sc,       &lds[1][1][tid * 16]);
  GLDS(Bg + (size_t)(128 + sr) * K_ + BK + sc, &lds[1][1][8192 + tid * 16]);
  VM_WAIT(2);
  __builtin_amdgcn_s_barrier();
  MEMFENCE;

  for (int T = 0; T < NT - 2; ++T)
    tile_step<0>(T, lds, acc, Ag, Bg, wm, wn, lrow, hi2, tid);
  tile_step<1>(NT - 2, lds, acc, Ag, Bg, wm, wn, lrow, hi2, tid);
  tile_step<2>(NT - 1, lds, acc, Ag, Bg, wm, wn, lrow, hi2, tid);

  // epilogue: C/D layout col = lane&15, row = (lane>>4)*4 + reg  (shape-
  // determined, dtype-independent).  out = acc * sx[row] * sw[col].
  const int crow = brow + wm * 128 + hi2 * 4;
  const int ccol = bcol + wn * 64 + lrow;
  float swv[4];
#pragma unroll
  for (int n = 0; n < 4; ++n) swv[n] = sw[ccol + n * 16];
#pragma unroll
  for (int m = 0; m < 8; ++m)
#pragma unroll
    for (int r = 0; r < 4; ++r) {
      const int row = crow + m * 16 + r;
      const float sxv = sx[row];
#pragma unroll
      for (int n = 0; n < 4; ++n)
        C[(size_t)row * N_ + ccol + n * 16] = (float)acc[m][n][r] * sxv * swv[n];
    }
}

// ---------------------------------------------------------------------------
// Fallback (ws too small): fp32 tiled GEMM with on-the-fly dequant
// ---------------------------------------------------------------------------
__global__ __launch_bounds__(256) void fallback_kernel(
    const float* __restrict__ x, const float* __restrict__ cb,
    const float* __restrict__ scales, const int* __restrict__ idx,
    const int* __restrict__ signs, float* __restrict__ out)
{
  __shared__ float Xs[32][33];
  __shared__ float Ws[32][33];
  const int t = threadIdx.x;
  const int tx = t & 31, ty = t >> 5;
  const int brow = blockIdx.y * 32, bcol = blockIdx.x * 32;
  float acc[4] = {0.f, 0.f, 0.f, 0.f};

  for (int k0 = 0; k0 < K_; k0 += 32) {
    for (int l = t; l < 1024; l += 256) {
      const int r = l >> 5, c = l & 31;
      Xs[r][c] = x[(size_t)(brow + r) * K_ + k0 + c];
      const int n = bcol + r;
      const size_t flat = (size_t)n * K_ + (k0 + c);
      const int g = (int)(flat >> 3), j = (int)(flat & 7);
      float wv = cb[idx[g] * 8 + j] * scales[n];
      if (!((signs[g] >> (7 - j)) & 1)) wv = -wv;
      Ws[r][c] = wv;
    }
    __syncthreads();
#pragma unroll
    for (int kk = 0; kk < 32; ++kk) {
      const float wv = Ws[tx][kk];
      acc[0] += Xs[ty][kk] * wv;
      acc[1] += Xs[ty + 8][kk] * wv;
      acc[2] += Xs[ty + 16][kk] * wv;
      acc[3] += Xs[ty + 24][kk] * wv;
    }
    __syncthreads();
  }
#pragma unroll
  for (int q = 0; q < 4; ++q)
    out[(size_t)(brow + ty + 8 * q) * N_ + bcol + tx] = acc[q];
}

// ---------------------------------------------------------------------------
extern "C" void kernel_launch(void* const* d_in, const int* in_sizes, int n_in,
                              void* d_out, int out_size, void* d_ws, size_t ws_size,
                              hipStream_t stream)
{
  const float* x      = (const float*)d_in[0];
  const float* cb     = (const float*)d_in[1];
  const float* scales = (const float*)d_in[2];
  const int*   idx    = (const int*)d_in[3];
  const int*   signs  = (const int*)d_in[4];
  float* out = (float*)d_out;

  const size_t wq = (size_t)N_ * K_;        // 16.8 MB i8
  const size_t xq = (size_t)M_ * K_;        // 33.6 MB i8
  const size_t need = wq + xq + (N_ + M_) * sizeof(float);

  if (ws_size >= need) {
    signed char* Wq = (signed char*)d_ws;
    signed char* Xq = Wq + wq;
    float* swp = (float*)(Xq + xq);
    float* sxp = swp + N_;
    prep_kernel<<<N_ + M_, 256, 0, stream>>>(x, cb, scales, idx, signs, Wq, Xq, swp, sxp);
    gemmq_kernel<<<(M_ / BM) * (N_ / BN), 512, 0, stream>>>(Xq, Wq, sxp, swp, out);
  } else {
    fallback_kernel<<<dim3(N_ / 32, M_ / 32), 256, 0, stream>>>(x, cb, scales, idx, signs, out);
  }
}

// Round 11
// 186.863 us; speedup vs baseline: 1.9172x; 1.0173x over previous
//
#include <hip/hip_runtime.h>

// SymHQLinear: out[8192,4096] = x @ W^T; W[4096,4096] dequantized from
// codebook[4096,8] + per-row scales + packed sign bits.
// Strategy: per-row symmetric i8 quantization of X and W, mfma_i32_16x16x64_i8
// GEMM, fp32 epilogue scales.  R11: LDS chunk swizzle c^=(row>>1)&3 kills the
// quarter-wave 8-way bank conflict found in R10 (1.26e7 conflicts).
#define M_ 8192   // TOKENS
#define N_ 4096   // OUT
#define K_ 4096   // IN

typedef float f32x4 __attribute__((ext_vector_type(4)));
typedef int   i32x4 __attribute__((ext_vector_type(4)));

// ---------------------------------------------------------------------------
// Kernel 1 (fused prep): blocks [0, 4096): W row -> dequant, row-max, i8 + sw
//                        blocks [4096, 12288): X row -> row-max, i8 + sx
// ---------------------------------------------------------------------------
__device__ __forceinline__ unsigned pack4(const float* v, float inv) {
  unsigned r = 0;
#pragma unroll
  for (int j = 0; j < 4; ++j) {
    int q = (int)rintf(v[j] * inv);
    q = q < -127 ? -127 : (q > 127 ? 127 : q);
    r |= ((unsigned)(q & 0xff)) << (8 * j);
  }
  return r;
}

__global__ __launch_bounds__(256) void prep_kernel(
    const float* __restrict__ x, const float* __restrict__ cb,
    const float* __restrict__ scales, const int* __restrict__ idx,
    const int* __restrict__ signs,
    signed char* __restrict__ Wq, signed char* __restrict__ Xq,
    float* __restrict__ sw, float* __restrict__ sx)
{
  __shared__ float wred[4];
  const int b = blockIdx.x, t = threadIdx.x;

  if (b < N_) {
    // ---- W row b: 512 groups; thread handles groups t and t+256 ----
    const float s = scales[b];
    const int g0 = b * 512 + t, g1 = g0 + 256;
    const int c0 = idx[g0], c1 = idx[g1];
    const int sb0 = signs[g0], sb1 = signs[g1];
    const float* cv0 = cb + c0 * 8;
    const float* cv1 = cb + c1 * 8;
    float v[16];
    float mx = 0.f;
#pragma unroll
    for (int j = 0; j < 8; ++j) {
      float a = cv0[j] * s;
      if (!((sb0 >> (7 - j)) & 1)) a = -a;
      v[j] = a; mx = fmaxf(mx, fabsf(a));
    }
#pragma unroll
    for (int j = 0; j < 8; ++j) {
      float a = cv1[j] * s;
      if (!((sb1 >> (7 - j)) & 1)) a = -a;
      v[8 + j] = a; mx = fmaxf(mx, fabsf(a));
    }
#pragma unroll
    for (int off = 1; off < 64; off <<= 1) mx = fmaxf(mx, __shfl_xor(mx, off));
    if ((t & 63) == 0) wred[t >> 6] = mx;
    __syncthreads();
    mx = fmaxf(fmaxf(wred[0], wred[1]), fmaxf(wred[2], wred[3]));
    mx = fmaxf(mx, 1e-20f);
    const float inv = 127.0f / mx;
    if (t == 0) sw[b] = mx / 127.0f;
    uint2 o0 = {pack4(v, inv),     pack4(v + 4, inv)};
    uint2 o1 = {pack4(v + 8, inv), pack4(v + 12, inv)};
    *(uint2*)(Wq + (size_t)b * K_ + t * 8)        = o0;
    *(uint2*)(Wq + (size_t)b * K_ + 2048 + t * 8) = o1;
  } else {
    // ---- X row r: 4096 elems; thread handles 16 ----
    const int r = b - N_;
    const f32x4* px = (const f32x4*)(x + (size_t)r * K_ + t * 16);
    f32x4 a0 = px[0], a1 = px[1], a2 = px[2], a3 = px[3];
    float v[16];
#pragma unroll
    for (int j = 0; j < 4; ++j) { v[j] = a0[j]; v[4 + j] = a1[j]; v[8 + j] = a2[j]; v[12 + j] = a3[j]; }
    float mx = 0.f;
#pragma unroll
    for (int j = 0; j < 16; ++j) mx = fmaxf(mx, fabsf(v[j]));
#pragma unroll
    for (int off = 1; off < 64; off <<= 1) mx = fmaxf(mx, __shfl_xor(mx, off));
    if ((t & 63) == 0) wred[t >> 6] = mx;
    __syncthreads();
    mx = fmaxf(fmaxf(wred[0], wred[1]), fmaxf(wred[2], wred[3]));
    mx = fmaxf(mx, 1e-20f);
    const float inv = 127.0f / mx;
    if (t == 0) sx[r] = mx / 127.0f;
    uint4 o = {pack4(v, inv), pack4(v + 4, inv), pack4(v + 8, inv), pack4(v + 12, inv)};
    *(uint4*)(Xq + (size_t)r * K_ + t * 16) = o;
  }
}

// ---------------------------------------------------------------------------
// Kernel 2: 256x256x64 i8 GEMM, 2 phases/tile, mfma_i32_16x16x64_i8.
// LDS 64 KiB: [2 bufs][A|B][256 x 64 i8].
// SWIZZLE (R11): 16B-chunk c' = c ^ ((row>>1)&3).  Quarter-wave bank audit:
// lanes 0-15 read rows 0-15 at one chunk; swizzled, rows 0-7 cover all 8
// bank-quads, rows 8-15 repeat -> 2 lanes/quad = free (m136).  Fragment-row
// bases are multiples of 16 so (row>>1)&3 == (lrow>>1)&3: per-lane constant.
// Both-sides (rule 21): linear GLDS dest + inverse-swizzled global SOURCE col
// (involution) + swizzled read chunk.
//   P0: read A-lo(4)+B(4); stage A(T+1)->nb ; BAR; lgkm0; 16 MFMA; BAR
//   P1: read A-hi(4);      stage B(T+2)->b  ; BAR; lgkm0; 16 MFMA; vmcnt(2); BAR
// vmcnt @ T P1-end: oldest [B(T+1):2][A(T+1):2][B(T+2):2] -> keep 2 drains
// all tile-(T+1) data.  Prologue: [A0:2][B0:2][B1:2], vmcnt(2) drains tile 0.
// ---------------------------------------------------------------------------
#define BM 256
#define BN 256
#define BK 64
#define NT (K_ / BK)          // 64 K-tiles

#define GLDS(g, l) __builtin_amdgcn_global_load_lds( \
    (const __attribute__((address_space(1))) void*)(g), \
    (__attribute__((address_space(3))) void*)(l), 16, 0, 0)

#define LGKM0 do { \
    asm volatile("s_waitcnt lgkmcnt(0)" ::: "memory"); \
    __builtin_amdgcn_sched_barrier(0); \
  } while (0)

#define VM_WAIT(n) asm volatile("s_waitcnt vmcnt(" #n ")" ::: "memory")
#define MEMFENCE asm volatile("" ::: "memory")

// MODE: 0 steady, 1 = T==NT-2, 2 = T==NT-1
template<int MODE>
__device__ __forceinline__ void tile_step(
    int T, signed char (*lds)[2][16384], i32x4 (&acc)[8][4],
    const signed char* __restrict__ Ag,
    const signed char* __restrict__ Bg,
    int wm, int wn, int lrow, int cs16,   // cs16 = (hi2 ^ ((lrow>>1)&3)) * 16
    int tid, int sr, int scs)             // scs = inv-swizzled staging col
{
  const int b = T & 1, nb = b ^ 1;
  i32x4 av[4], bv[4];

  // ================= P0: read A-lo(4)+B(4); stage A(T+1) =================
#pragma unroll
  for (int m = 0; m < 4; ++m)
    av[m] = *(const i32x4*)(const void*)(
        &lds[b][0][(wm * 128 + m * 16 + lrow) * 64 + cs16]);
#pragma unroll
  for (int n = 0; n < 4; ++n)
    bv[n] = *(const i32x4*)(const void*)(
        &lds[b][1][(wn * 64 + n * 16 + lrow) * 64 + cs16]);
  if (MODE <= 1) {
    GLDS(Ag + (size_t)(sr) * K_ + (T + 1) * BK + scs,       &lds[nb][0][tid * 16]);
    GLDS(Ag + (size_t)(128 + sr) * K_ + (T + 1) * BK + scs, &lds[nb][0][8192 + tid * 16]);
  }
  __builtin_amdgcn_s_barrier();
  LGKM0;
  __builtin_amdgcn_s_setprio(1);
#pragma unroll
  for (int n = 0; n < 4; ++n)
#pragma unroll
    for (int m = 0; m < 4; ++m)
      acc[m][n] = __builtin_amdgcn_mfma_i32_16x16x64_i8(av[m], bv[n], acc[m][n], 0, 0, 0);
  __builtin_amdgcn_s_setprio(0);
  __builtin_amdgcn_s_barrier();
  MEMFENCE;

  // ================= P1: read A-hi(4); stage B(T+2); vmcnt ================
#pragma unroll
  for (int m = 0; m < 4; ++m)
    av[m] = *(const i32x4*)(const void*)(
        &lds[b][0][(wm * 128 + 64 + m * 16 + lrow) * 64 + cs16]);
  if (MODE == 0) {
    GLDS(Bg + (size_t)(sr) * K_ + (T + 2) * BK + scs,       &lds[b][1][tid * 16]);
    GLDS(Bg + (size_t)(128 + sr) * K_ + (T + 2) * BK + scs, &lds[b][1][8192 + tid * 16]);
  }
  __builtin_amdgcn_s_barrier();
  LGKM0;
  __builtin_amdgcn_s_setprio(1);
#pragma unroll
  for (int n = 0; n < 4; ++n)
#pragma unroll
    for (int m = 0; m < 4; ++m)
      acc[4 + m][n] = __builtin_amdgcn_mfma_i32_16x16x64_i8(av[m], bv[n], acc[4 + m][n], 0, 0, 0);
  __builtin_amdgcn_s_setprio(0);
  if (MODE == 0)      VM_WAIT(2);     // drains all tile-(T+1) data (ledger)
  else if (MODE == 1) VM_WAIT(0);     // drains A(NT-1), B(NT-1)
  __builtin_amdgcn_s_barrier();
  MEMFENCE;
}

__global__ __launch_bounds__(512, 2) void gemmq_kernel(
    const signed char* __restrict__ A,   // Xq [M_][K_] i8
    const signed char* __restrict__ B,   // Wq [N_][K_] i8
    const float* __restrict__ sx, const float* __restrict__ sw,
    float* __restrict__ C)
{
  __shared__ signed char lds[2][2][16384];  // 64 KiB

  // XCD-aware bijective swizzle (nwg = 512, 512 % 8 == 0)
  const int nwg = (M_ / BM) * (N_ / BN);
  const int bid = blockIdx.x;
  const int wg  = (bid % 8) * (nwg / 8) + bid / 8;
  const int tn  = wg % (N_ / BN);
  const int tm  = wg / (N_ / BN);
  const int brow = tm * BM, bcol = tn * BN;

  const int tid  = threadIdx.x;
  const int lane = tid & 63, w = tid >> 6;
  const int wm   = w >> 2, wn = w & 3;      // 2 (M) x 4 (N)
  const int lrow = lane & 15, hi2 = lane >> 4;
  const int cs16 = (hi2 ^ ((lrow >> 1) & 3)) * 16;       // swizzled read chunk
  const int sr  = tid >> 2;
  const int scs = ((tid & 3) ^ ((tid >> 3) & 3)) * 16;   // inv-swizzled source

  const signed char* Ag = A + (size_t)brow * K_;
  const signed char* Bg = B + (size_t)bcol * K_;

  i32x4 acc[8][4];
#pragma unroll
  for (int m = 0; m < 8; ++m)
#pragma unroll
    for (int n = 0; n < 4; ++n)
      acc[m][n] = i32x4{0, 0, 0, 0};

  // ---- prologue: [A(0):2][B(0):2][B(1):2]; vmcnt(2) drains tile 0 ----
  GLDS(Ag + (size_t)(sr) * K_ + scs,            &lds[0][0][tid * 16]);
  GLDS(Ag + (size_t)(128 + sr) * K_ + scs,      &lds[0][0][8192 + tid * 16]);
  GLDS(Bg + (size_t)(sr) * K_ + scs,            &lds[0][1][tid * 16]);
  GLDS(Bg + (size_t)(128 + sr) * K_ + scs,      &lds[0][1][8192 + tid * 16]);
  GLDS(Bg + (size_t)(sr) * K_ + BK + scs,       &lds[1][1][tid * 16]);
  GLDS(Bg + (size_t)(128 + sr) * K_ + BK + scs, &lds[1][1][8192 + tid * 16]);
  VM_WAIT(2);
  __builtin_amdgcn_s_barrier();
  MEMFENCE;

  for (int T = 0; T < NT - 2; ++T)
    tile_step<0>(T, lds, acc, Ag, Bg, wm, wn, lrow, cs16, tid, sr, scs);
  tile_step<1>(NT - 2, lds, acc, Ag, Bg, wm, wn, lrow, cs16, tid, sr, scs);
  tile_step<2>(NT - 1, lds, acc, Ag, Bg, wm, wn, lrow, cs16, tid, sr, scs);

  // epilogue: C/D layout col = lane&15, row = (lane>>4)*4 + reg  (shape-
  // determined, dtype-independent).  out = acc * sx[row] * sw[col].
  const int crow = brow + wm * 128 + hi2 * 4;
  const int ccol = bcol + wn * 64 + lrow;
  float swv[4];
#pragma unroll
  for (int n = 0; n < 4; ++n) swv[n] = sw[ccol + n * 16];
#pragma unroll
  for (int m = 0; m < 8; ++m)
#pragma unroll
    for (int r = 0; r < 4; ++r) {
      const int row = crow + m * 16 + r;
      const float sxv = sx[row];
#pragma unroll
      for (int n = 0; n < 4; ++n)
        C[(size_t)row * N_ + ccol + n * 16] = (float)acc[m][n][r] * sxv * swv[n];
    }
}

// ---------------------------------------------------------------------------
// Fallback (ws too small): fp32 tiled GEMM with on-the-fly dequant
// ---------------------------------------------------------------------------
__global__ __launch_bounds__(256) void fallback_kernel(
    const float* __restrict__ x, const float* __restrict__ cb,
    const float* __restrict__ scales, const int* __restrict__ idx,
    const int* __restrict__ signs, float* __restrict__ out)
{
  __shared__ float Xs[32][33];
  __shared__ float Ws[32][33];
  const int t = threadIdx.x;
  const int tx = t & 31, ty = t >> 5;
  const int brow = blockIdx.y * 32, bcol = blockIdx.x * 32;
  float acc[4] = {0.f, 0.f, 0.f, 0.f};

  for (int k0 = 0; k0 < K_; k0 += 32) {
    for (int l = t; l < 1024; l += 256) {
      const int r = l >> 5, c = l & 31;
      Xs[r][c] = x[(size_t)(brow + r) * K_ + k0 + c];
      const int n = bcol + r;
      const size_t flat = (size_t)n * K_ + (k0 + c);
      const int g = (int)(flat >> 3), j = (int)(flat & 7);
      float wv = cb[idx[g] * 8 + j] * scales[n];
      if (!((signs[g] >> (7 - j)) & 1)) wv = -wv;
      Ws[r][c] = wv;
    }
    __syncthreads();
#pragma unroll
    for (int kk = 0; kk < 32; ++kk) {
      const float wv = Ws[tx][kk];
      acc[0] += Xs[ty][kk] * wv;
      acc[1] += Xs[ty + 8][kk] * wv;
      acc[2] += Xs[ty + 16][kk] * wv;
      acc[3] += Xs[ty + 24][kk] * wv;
    }
    __syncthreads();
  }
#pragma unroll
  for (int q = 0; q < 4; ++q)
    out[(size_t)(brow + ty + 8 * q) * N_ + bcol + tx] = acc[q];
}

// ---------------------------------------------------------------------------
extern "C" void kernel_launch(void* const* d_in, const int* in_sizes, int n_in,
                              void* d_out, int out_size, void* d_ws, size_t ws_size,
                              hipStream_t stream)
{
  const float* x      = (const float*)d_in[0];
  const float* cb     = (const float*)d_in[1];
  const float* scales = (const float*)d_in[2];
  const int*   idx    = (const int*)d_in[3];
  const int*   signs  = (const int*)d_in[4];
  float* out = (float*)d_out;

  const size_t wq = (size_t)N_ * K_;        // 16.8 MB i8
  const size_t xq = (size_t)M_ * K_;        // 33.6 MB i8
  const size_t need = wq + xq + (N_ + M_) * sizeof(float);

  if (ws_size >= need) {
    signed char* Wq = (signed char*)d_ws;
    signed char* Xq = Wq + wq;
    float* swp = (float*)(Xq + xq);
    float* sxp = swp + N_;
    prep_kernel<<<N_ + M_, 256, 0, stream>>>(x, cb, scales, idx, signs, Wq, Xq, swp, sxp);
    gemmq_kernel<<<(M_ / BM) * (N_ / BN), 512, 0, stream>>>(Xq, Wq, sxp, swp, out);
  } else {
    fallback_kernel<<<dim3(N_ / 32, M_ / 32), 256, 0, stream>>>(x, cb, scales, idx, signs, out);
  }
}